// Round 12
// baseline (105.591 us; speedup 1.0000x reference)
//
#include <hip/hip_runtime.h>

#define HW 128
#define XBb 16          // byte offset of x buffer in LDS (16B pad before)
#define KTb 32784       // byte offset of ktab (16 + 16*2048)

typedef __attribute__((ext_vector_type(8))) short  bfrag;   // 8 bf16
typedef __attribute__((ext_vector_type(16))) float f16x;    // 32x32 accumulator
typedef __attribute__((ext_vector_type(4)))  float f4;

__device__ __forceinline__ float lrelu(float x) { return x > 0.f ? x : 0.1f * x; }

__device__ __forceinline__ short f2bf(float f) {
    unsigned u = __builtin_bit_cast(unsigned, f);
    u = u + 0x7FFFu + ((u >> 16) & 1u);
    return (short)(u >> 16);
}
__device__ __forceinline__ float bf2f(short s) {
    return __builtin_bit_cast(float, (unsigned)(unsigned short)s << 16);
}

__device__ float g_ktab[32 * 768];                // [b][rr][g][j][12] att-folded taps
__device__ short g_whi[4096], g_wlo[4096];        // conv_w bf16 hi/lo, [o*64+c]

// ---------- prep: b<32 -> att-folded kernels; b==32 -> W hi/lo split ----------
__global__ __launch_bounds__(64) void dgfem_prep(
    const float* __restrict__ v, const float* __restrict__ ca_w1,
    const float* __restrict__ ca_w2, const float* __restrict__ k_w1,
    const float* __restrict__ k_w2, const float* __restrict__ conv_w)
{
    const int b = blockIdx.x;
    const int t = threadIdx.x;           // 64 threads

    if (b == 32) {
        for (int i = t; i < 4096; i += 64) {
            float wv = conv_w[i];
            short hi = f2bf(wv);
            short lo = f2bf(wv - bf2f(hi));
            g_whi[i] = hi;
            g_wlo[i] = lo;
        }
        return;
    }

    __shared__ float vb[64], t1[8], att[64], t2[64];
    vb[t] = v[b * 64 + t];
    __syncthreads();

    if (t < 8) {
        float s = 0.f;
        for (int j = 0; j < 64; ++j) s += vb[j] * ca_w1[t * 64 + j];
        t1[t] = lrelu(s);
    }
    {
        float s = 0.f;
        for (int j = 0; j < 64; ++j) s += vb[j] * k_w1[t * 64 + j];
        t2[t] = lrelu(s);
    }
    __syncthreads();
    {
        float s = 0.f;
        for (int i = 0; i < 8; ++i) s += t1[i] * ca_w2[t * 8 + i];
        att[t] = 1.f / (1.f + expf(-s));
    }
    __syncthreads();
    // fold att[c] into kernel (conv(x*a,k) == conv(x,a*k)); layout [rr][g][j][12]
    for (int r = t; r < 576; r += 64) {
        int c = r / 9, tp = r - c * 9;
        float s = 0.f;
        for (int j = 0; j < 64; ++j) s += t2[j] * k_w2[r * 64 + j];
        int rr = c >> 4, gg = (c >> 3) & 1, jj = c & 7;
        g_ktab[b * 768 + ((rr * 2 + gg) * 8 + jj) * 12 + tp] = s * att[c];
    }
}

#define GLUE2(a, b) a##b
#define GLUE(a, b) GLUE2(a, b)
#define CONT(K0, K1, K2, S) \
    fmaf(K0, GLUE(xL, S), fmaf(K1, GLUE(xC, S), (K2) * GLUE(xR, S)))

__global__ __launch_bounds__(256) void dgfem_main(
    const float* __restrict__ x0, const float* __restrict__ conv_b,
    float* __restrict__ out)
{
    const int t  = threadIdx.x;
    const int w  = t >> 6;               // wave -> px tile
    const int l  = t & 63;
    const int g  = l >> 5;               // k-half
    const int ln = l & 31;
    const int px = w * 32 + ln;

    // XCD swizzle (2048 % 8 == 0, bijective)
    const int bid  = blockIdx.x;
    const int orig = (bid & 7) * 256 + (bid >> 3);
    const int b    = orig >> 6;          // 0..31
    const int p    = orig & 63;          // row pair
    const int gy0  = p * 2;
    const int r0   = min(max(gy0 - 1, 0), 124);   // first staged input row

    __shared__ __align__(16) char lds[35856];
    float* ldsf = (float*)lds;
    (void)ldsf;

    // stage ktab (once)
    {
        const float* ksrc = g_ktab + b * 768;
        for (int i = t; i < 768; i += 256) *(float*)(lds + KTb + i * 4) = ksrc[i];
    }

    const char* xb = (const char*)x0 + ((size_t)b << 22);

    // stage 16 channels x 4 contiguous rows (2048 B) via 2 width-16 calls each
    #define STAGE(rr_)                                                         \
    {                                                                          \
        _Pragma("unroll")                                                      \
        for (int q = 0; q < 4; ++q) {                                          \
            const int cl = 4 * w + q;                                          \
            const char* src = xb + ((size_t)((rr_) * 16 + cl) << 16)           \
                              + r0 * 512 + (size_t)l * 16;                     \
            char* dst = lds + XBb + cl * 2048;                                 \
            __builtin_amdgcn_global_load_lds(                                  \
                (const __attribute__((address_space(1))) unsigned*)src,        \
                (__attribute__((address_space(3))) unsigned*)dst, 16, 0, 0);   \
            __builtin_amdgcn_global_load_lds(                                  \
                (const __attribute__((address_space(1))) unsigned*)(src+1024), \
                (__attribute__((address_space(3))) unsigned*)(dst+1024),       \
                16, 0, 0);                                                     \
        }                                                                      \
    }

    f16x acc00, acc01, acc10, acc11;
    #pragma unroll
    for (int i = 0; i < 16; ++i) {
        acc00[i] = 0.f; acc01[i] = 0.f; acc10[i] = 0.f; acc11[i] = 0.f;
    }

    const int   woffb = ln * 128 + g * 16;
    const float mLf = (px > 0)   ? 1.f : 0.f;
    const float mRf = (px < 127) ? 1.f : 0.f;

    #define RUN_ROUNDS(S00, S01, S02, S10, S11, S12, M00, M12)                 \
    do {                                                                       \
        STAGE(0);                                                              \
        __syncthreads();                                                       \
        _Pragma("unroll 1")                                                    \
        for (int rr = 0; rr < 4; ++rr) {                                       \
            bfrag yh0, yl0, yh1, yl1;                                          \
            _Pragma("unroll")                                                  \
            for (int j = 0; j < 8; ++j) {                                      \
                const f4* kf = (const f4*)(lds + KTb + ((rr * 2 + g) * 8 + j) * 48); \
                f4 kA = kf[0], kB = kf[1], kC = kf[2];                         \
                float k0 = kA.x, k1 = kA.y, k2 = kA.z, k3 = kA.w;              \
                float k4 = kB.x, k5 = kB.y, k6 = kB.z, k7 = kB.w, k8 = kC.x;   \
                const float* b1 = (const float*)(lds + XBb)                    \
                                  + (g * 8 + j) * 512 + px - 1;                \
                const float* b2 = b1 + 256;                                    \
                float xL0 = b1[0]   * mLf, xC0 = b1[1],   xR0 = b1[2]   * mRf; \
                float xL1 = b1[128] * mLf, xC1 = b1[129], xR1 = b1[130] * mRf; \
                float xL2 = b2[0]   * mLf, xC2 = b2[1],   xR2 = b2[2]   * mRf; \
                float xL3 = b2[128] * mLf, xC3 = b2[129], xR3 = b2[130] * mRf; \
                float a0 = ((M00) ? 0.f : CONT(k0, k1, k2, S00))               \
                         + CONT(k3, k4, k5, S01) + CONT(k6, k7, k8, S02);      \
                float a1 = CONT(k0, k1, k2, S10) + CONT(k3, k4, k5, S11)       \
                         + ((M12) ? 0.f : CONT(k6, k7, k8, S12));              \
                a0 = lrelu(a0); a1 = lrelu(a1);                                \
                unsigned u0 = __builtin_bit_cast(unsigned, a0);                \
                float h0f = __builtin_bit_cast(float, u0 & 0xFFFF0000u);       \
                yh0[j] = (short)(u0 >> 16);                                    \
                yl0[j] = (short)(__builtin_bit_cast(unsigned, a0 - h0f) >> 16);\
                unsigned u1 = __builtin_bit_cast(unsigned, a1);                \
                float h1f = __builtin_bit_cast(float, u1 & 0xFFFF0000u);       \
                yh1[j] = (short)(u1 >> 16);                                    \
                yl1[j] = (short)(__builtin_bit_cast(unsigned, a1 - h1f) >> 16);\
            }                                                                  \
            __syncthreads();               /* all waves done reading xbuf */   \
            if (rr < 3) STAGE(rr + 1);     /* issue next stage early */        \
            const char* whb = (const char*)g_whi + woffb + rr * 32;            \
            const char* wlb = (const char*)g_wlo + woffb + rr * 32;            \
            bfrag whi0 = *(const bfrag*)(whb);                                 \
            bfrag whi1 = *(const bfrag*)(whb + 4096);                          \
            bfrag wlo0 = *(const bfrag*)(wlb);                                 \
            bfrag wlo1 = *(const bfrag*)(wlb + 4096);                          \
            acc00 = __builtin_amdgcn_mfma_f32_32x32x16_bf16(whi0, yh0, acc00, 0, 0, 0); \
            acc00 = __builtin_amdgcn_mfma_f32_32x32x16_bf16(whi0, yl0, acc00, 0, 0, 0); \
            acc00 = __builtin_amdgcn_mfma_f32_32x32x16_bf16(wlo0, yh0, acc00, 0, 0, 0); \
            acc01 = __builtin_amdgcn_mfma_f32_32x32x16_bf16(whi1, yh0, acc01, 0, 0, 0); \
            acc01 = __builtin_amdgcn_mfma_f32_32x32x16_bf16(whi1, yl0, acc01, 0, 0, 0); \
            acc01 = __builtin_amdgcn_mfma_f32_32x32x16_bf16(wlo1, yh0, acc01, 0, 0, 0); \
            acc10 = __builtin_amdgcn_mfma_f32_32x32x16_bf16(whi0, yh1, acc10, 0, 0, 0); \
            acc10 = __builtin_amdgcn_mfma_f32_32x32x16_bf16(whi0, yl1, acc10, 0, 0, 0); \
            acc10 = __builtin_amdgcn_mfma_f32_32x32x16_bf16(wlo0, yh1, acc10, 0, 0, 0); \
            acc11 = __builtin_amdgcn_mfma_f32_32x32x16_bf16(whi1, yh1, acc11, 0, 0, 0); \
            acc11 = __builtin_amdgcn_mfma_f32_32x32x16_bf16(whi1, yl1, acc11, 0, 0, 0); \
            acc11 = __builtin_amdgcn_mfma_f32_32x32x16_bf16(wlo1, yh1, acc11, 0, 0, 0); \
            if (rr < 3) __syncthreads();   /* stage drained (vmcnt0+barrier) */\
        }                                                                      \
    } while (0)

    // slot maps (compile-time per variant; block-uniform branch)
    if (p > 0 && p < 63)      RUN_ROUNDS(0, 1, 2, 1, 2, 3, 0, 0);
    else if (p == 0)          RUN_ROUNDS(0, 0, 1, 0, 1, 2, 1, 0);
    else                      RUN_ROUNDS(1, 2, 3, 2, 3, 3, 0, 1);

    #undef RUN_ROUNDS
    #undef STAGE

    // epilogue: D layout col=lane&31, row=(reg&3)+8*(reg>>2)+4*(lane>>5)  [verified 4x]
    float* ob0 = out + ((size_t)b << 20) + (size_t)gy0 * HW + px;
    float* ob1 = ob0 + HW;
    #pragma unroll
    for (int q = 0; q < 4; ++q) {
        const int obase = 8 * q + 4 * g;
        float4 bv0 = *(const float4*)&conv_b[obase];
        float4 bv1 = *(const float4*)&conv_b[32 + obase];
        const float* b0f = (const float*)&bv0;
        const float* b1f = (const float*)&bv1;
        #pragma unroll
        for (int r2 = 0; r2 < 4; ++r2) {
            ob0[(size_t)(obase + r2) * 16384]      = acc00[q * 4 + r2] + b0f[r2];
            ob0[(size_t)(32 + obase + r2) * 16384] = acc01[q * 4 + r2] + b1f[r2];
            ob1[(size_t)(obase + r2) * 16384]      = acc10[q * 4 + r2] + b0f[r2];
            ob1[(size_t)(32 + obase + r2) * 16384] = acc11[q * 4 + r2] + b1f[r2];
        }
    }
}

extern "C" void kernel_launch(void* const* d_in, const int* in_sizes, int n_in,
                              void* d_out, int out_size, void* d_ws, size_t ws_size,
                              hipStream_t stream) {
    const float* x0     = (const float*)d_in[0];
    const float* v      = (const float*)d_in[1];
    const float* ca_w1  = (const float*)d_in[2];
    const float* ca_w2  = (const float*)d_in[3];
    const float* k_w1   = (const float*)d_in[4];
    const float* k_w2   = (const float*)d_in[5];
    const float* conv_w = (const float*)d_in[6];
    const float* conv_b = (const float*)d_in[7];
    float* outp = (float*)d_out;

    dgfem_prep<<<dim3(33), dim3(64), 0, stream>>>(v, ca_w1, ca_w2, k_w1, k_w2, conv_w);
    dgfem_main<<<dim3(2048), dim3(256), 0, stream>>>(x0, conv_b, outp);
}

// Round 13
// 90.342 us; speedup vs baseline: 1.1688x; 1.1688x over previous
//
#include <hip/hip_runtime.h>

#define HW 128
#define XBb 16           // byte offset of x double-buffer (16B pad before)
#define XBf 4            // same, in floats
#define KTb 49168        // byte offset of ktab = 16 + 2*24576
#define LDS_BYTES 52240  // 49168 + 3072

typedef __attribute__((ext_vector_type(8))) short  bfrag;   // 8 bf16
typedef __attribute__((ext_vector_type(16))) float f16x;    // 32x32 accumulator
typedef __attribute__((ext_vector_type(4)))  float f4;

__device__ __forceinline__ float lrelu(float x) { return x > 0.f ? x : 0.1f * x; }

__device__ __forceinline__ short f2bf(float f) {
    unsigned u = __builtin_bit_cast(unsigned, f);
    u = u + 0x7FFFu + ((u >> 16) & 1u);
    return (short)(u >> 16);
}
__device__ __forceinline__ float bf2f(short s) {
    return __builtin_bit_cast(float, (unsigned)(unsigned short)s << 16);
}

__device__ float g_ktab[32 * 768];                // [b][rr][g][j][12] att-folded taps
__device__ short g_whi[4096], g_wlo[4096];        // conv_w bf16 hi/lo, [o*64+c]

// ---------- prep: b<32 -> att-folded kernels; b==32 -> W hi/lo split ----------
__global__ __launch_bounds__(64) void dgfem_prep(
    const float* __restrict__ v, const float* __restrict__ ca_w1,
    const float* __restrict__ ca_w2, const float* __restrict__ k_w1,
    const float* __restrict__ k_w2, const float* __restrict__ conv_w)
{
    const int b = blockIdx.x;
    const int t = threadIdx.x;           // 64 threads

    if (b == 32) {
        for (int i = t; i < 4096; i += 64) {
            float wv = conv_w[i];
            short hi = f2bf(wv);
            short lo = f2bf(wv - bf2f(hi));
            g_whi[i] = hi;
            g_wlo[i] = lo;
        }
        return;
    }

    __shared__ float vb[64], t1[8], att[64], t2[64];
    vb[t] = v[b * 64 + t];
    __syncthreads();

    if (t < 8) {
        float s = 0.f;
        for (int j = 0; j < 64; ++j) s += vb[j] * ca_w1[t * 64 + j];
        t1[t] = lrelu(s);
    }
    {
        float s = 0.f;
        for (int j = 0; j < 64; ++j) s += vb[j] * k_w1[t * 64 + j];
        t2[t] = lrelu(s);
    }
    __syncthreads();
    {
        float s = 0.f;
        for (int i = 0; i < 8; ++i) s += t1[i] * ca_w2[t * 8 + i];
        att[t] = 1.f / (1.f + expf(-s));
    }
    __syncthreads();
    // fold att[c] into kernel; layout [rr][g][j][12]
    for (int r = t; r < 576; r += 64) {
        int c = r / 9, tp = r - c * 9;
        float s = 0.f;
        for (int j = 0; j < 64; ++j) s += t2[j] * k_w2[r * 64 + j];
        int rr = c >> 4, gg = (c >> 3) & 1, jj = c & 7;
        g_ktab[b * 768 + ((rr * 2 + gg) * 8 + jj) * 12 + tp] = s * att[c];
    }
}

__global__ __launch_bounds__(256) void dgfem_main(
    const float* __restrict__ x0, const float* __restrict__ conv_b,
    float* __restrict__ out)
{
    const int t  = threadIdx.x;
    const int w  = t >> 6;               // wave -> px tile
    const int l  = t & 63;
    const int g  = l >> 5;               // k-half
    const int ln = l & 31;
    const int px = w * 32 + ln;

    // XCD swizzle (4096 % 8 == 0, bijective)
    const int bid  = blockIdx.x;
    const int orig = (bid & 7) * 512 + (bid >> 3);
    const int b    = orig >> 7;          // 0..31
    const int gy   = orig & 127;         // output row

    // contiguous staged rows r0..r0+2; block-uniform slot offsets (floats)
    const int r0 = min(max(gy - 1, 0), 125);
    const int sA = (min(max(gy - 1, 0), 127) - r0) * 128;
    const int sB = (gy - r0) * 128;
    const int sC = (min(gy + 1, 127) - r0) * 128;
    const float rm0 = (gy > 0)   ? 1.f : 0.f;
    const float rm2 = (gy < 127) ? 1.f : 0.f;

    __shared__ __align__(16) char lds[LDS_BYTES];
    float* ldsf = (float*)lds;

    // stage ktab with row masks folded in (masked row taps -> 0)
    {
        const float* ksrc = g_ktab + b * 768;
        for (int i = t; i < 768; i += 256) {
            int tp = i % 12;
            float val = ksrc[i];
            float rm = (tp < 3) ? rm0 : ((tp < 6) ? 1.f : rm2);
            *(float*)(lds + KTb + i * 4) = (tp < 9) ? val * rm : 0.f;
        }
    }

    // per-lane staging source offsets (6 width-16 calls cover 4ch x 1536B)
    const int l16 = l * 16;
    int oq[1]; (void)oq;
    #define SRCOFF(q) ((((q) * 1024 + l16) / 1536) * 65536 + (((q) * 1024 + l16) % 1536))
    const int o0 = SRCOFF(0), o1 = SRCOFF(1), o2 = SRCOFF(2);
    const int o3 = SRCOFF(3), o4 = SRCOFF(4), o5 = SRCOFF(5);
    #undef SRCOFF

    const char* xb = (const char*)x0 + ((size_t)b << 22);

    #define STAGE(rr_, sel_)                                                   \
    {                                                                          \
        const char* base = xb + ((size_t)((rr_) * 16 + w * 4) << 16)           \
                           + (size_t)r0 * 512;                                 \
        char* dstb = lds + XBb + (sel_) * 24576 + w * 6144;                    \
        __builtin_amdgcn_global_load_lds(                                      \
            (const __attribute__((address_space(1))) unsigned*)(base + o0),    \
            (__attribute__((address_space(3))) unsigned*)(dstb), 16, 0, 0);    \
        __builtin_amdgcn_global_load_lds(                                      \
            (const __attribute__((address_space(1))) unsigned*)(base + o1),    \
            (__attribute__((address_space(3))) unsigned*)(dstb + 1024), 16, 0, 0); \
        __builtin_amdgcn_global_load_lds(                                      \
            (const __attribute__((address_space(1))) unsigned*)(base + o2),    \
            (__attribute__((address_space(3))) unsigned*)(dstb + 2048), 16, 0, 0); \
        __builtin_amdgcn_global_load_lds(                                      \
            (const __attribute__((address_space(1))) unsigned*)(base + o3),    \
            (__attribute__((address_space(3))) unsigned*)(dstb + 3072), 16, 0, 0); \
        __builtin_amdgcn_global_load_lds(                                      \
            (const __attribute__((address_space(1))) unsigned*)(base + o4),    \
            (__attribute__((address_space(3))) unsigned*)(dstb + 4096), 16, 0, 0); \
        __builtin_amdgcn_global_load_lds(                                      \
            (const __attribute__((address_space(1))) unsigned*)(base + o5),    \
            (__attribute__((address_space(3))) unsigned*)(dstb + 5120), 16, 0, 0); \
    }

    f16x acc0, acc1;
    #pragma unroll
    for (int i = 0; i < 16; ++i) { acc0[i] = 0.f; acc1[i] = 0.f; }

    const int   woffb = ln * 128 + g * 16;
    const float mLf = (px > 0)   ? 1.f : 0.f;
    const float mRf = (px < 127) ? 1.f : 0.f;

    STAGE(0, 0);
    __syncthreads();

    #pragma unroll 1
    for (int rr = 0; rr < 4; ++rr) {
        const int sel = rr & 1;
        if (rr < 3) STAGE(rr + 1, sel ^ 1);

        // row base pointers for this round (immediate-foldable per-j offsets)
        const float* xbase = ldsf + (XBf + sel * 6144 + g * 3072 + px - 1);
        const float* bA = xbase + sA;
        const float* bB = xbase + sB;
        const float* bC = xbase + sC;
        const char*  kb = lds + KTb + (rr * 2 + g) * 384;

        bfrag yh, yl;
        #pragma unroll
        for (int j = 0; j < 8; ++j) {
            const f4* kf = (const f4*)(kb + j * 48);
            f4 kA = kf[0], kB = kf[1], kC = kf[2];
            float xL0 = bA[j * 384]     * mLf;
            float xC0 = bA[j * 384 + 1];
            float xR0 = bA[j * 384 + 2] * mRf;
            float xL1 = bB[j * 384]     * mLf;
            float xC1 = bB[j * 384 + 1];
            float xR1 = bB[j * 384 + 2] * mRf;
            float xL2 = bC[j * 384]     * mLf;
            float xC2 = bC[j * 384 + 1];
            float xR2 = bC[j * 384 + 2] * mRf;
            float a = fmaf(kA.x, xL0, fmaf(kA.y, xC0, kA.z * xR0))
                    + fmaf(kA.w, xL1, fmaf(kB.x, xC1, kB.y * xR1))
                    + fmaf(kB.z, xL2, fmaf(kB.w, xC2, kC.x * xR2));
            a = lrelu(a);
            unsigned u  = __builtin_bit_cast(unsigned, a);
            float   hif = __builtin_bit_cast(float, u & 0xFFFF0000u);
            float   lof = a - hif;                   // exact residual
            yh[j] = (short)(u >> 16);
            yl[j] = (short)(__builtin_bit_cast(unsigned, lof) >> 16);
        }

        const char* whb = (const char*)g_whi + woffb + rr * 32;
        const char* wlb = (const char*)g_wlo + woffb + rr * 32;
        bfrag whi0 = *(const bfrag*)(whb);
        bfrag whi1 = *(const bfrag*)(whb + 4096);
        bfrag wlo0 = *(const bfrag*)(wlb);
        bfrag wlo1 = *(const bfrag*)(wlb + 4096);

        acc0 = __builtin_amdgcn_mfma_f32_32x32x16_bf16(whi0, yh, acc0, 0, 0, 0);
        acc0 = __builtin_amdgcn_mfma_f32_32x32x16_bf16(whi0, yl, acc0, 0, 0, 0);
        acc0 = __builtin_amdgcn_mfma_f32_32x32x16_bf16(wlo0, yh, acc0, 0, 0, 0);
        acc1 = __builtin_amdgcn_mfma_f32_32x32x16_bf16(whi1, yh, acc1, 0, 0, 0);
        acc1 = __builtin_amdgcn_mfma_f32_32x32x16_bf16(whi1, yl, acc1, 0, 0, 0);
        acc1 = __builtin_amdgcn_mfma_f32_32x32x16_bf16(wlo1, yh, acc1, 0, 0, 0);

        __syncthreads();   // stage rr+1 landed; all reads of buf sel done
    }
    #undef STAGE

    // epilogue: D layout col=lane&31, row=(reg&3)+8*(reg>>2)+4*(lane>>5)  [verified 5x]
    float* ob = out + ((size_t)b << 20) + (size_t)gy * HW + px;
    #pragma unroll
    for (int q = 0; q < 4; ++q) {
        const int obase = 8 * q + 4 * g;
        float4 bv0 = *(const float4*)&conv_b[obase];
        float4 bv1 = *(const float4*)&conv_b[32 + obase];
        const float* b0f = (const float*)&bv0;
        const float* b1f = (const float*)&bv1;
        #pragma unroll
        for (int r2 = 0; r2 < 4; ++r2) {
            ob[(size_t)(obase + r2) * 16384]      = acc0[q * 4 + r2] + b0f[r2];
            ob[(size_t)(32 + obase + r2) * 16384] = acc1[q * 4 + r2] + b1f[r2];
        }
    }
}

extern "C" void kernel_launch(void* const* d_in, const int* in_sizes, int n_in,
                              void* d_out, int out_size, void* d_ws, size_t ws_size,
                              hipStream_t stream) {
    const float* x0     = (const float*)d_in[0];
    const float* v      = (const float*)d_in[1];
    const float* ca_w1  = (const float*)d_in[2];
    const float* ca_w2  = (const float*)d_in[3];
    const float* k_w1   = (const float*)d_in[4];
    const float* k_w2   = (const float*)d_in[5];
    const float* conv_w = (const float*)d_in[6];
    const float* conv_b = (const float*)d_in[7];
    float* outp = (float*)d_out;

    dgfem_prep<<<dim3(33), dim3(64), 0, stream>>>(v, ca_w1, ca_w2, k_w1, k_w2, conv_w);
    dgfem_main<<<dim3(4096), dim3(256), 0, stream>>>(x0, conv_b, outp);
}

// Round 14
// 84.583 us; speedup vs baseline: 1.2484x; 1.0681x over previous
//
#include <hip/hip_runtime.h>

#define HW 128
#define XBb 16           // byte offset of x double-buffer (16B pad before)
#define XBf 4            // same, in floats
#define KTb 65552        // byte offset of ktab copies = 16 + 2*32768
#define LDS_BYTES 71696  // 65552 + 2*3072

typedef __attribute__((ext_vector_type(8))) short  bfrag;   // 8 bf16
typedef __attribute__((ext_vector_type(16))) float f16x;    // 32x32 accumulator
typedef __attribute__((ext_vector_type(4)))  float f4;

__device__ __forceinline__ float lrelu(float x) { return x > 0.f ? x : 0.1f * x; }

__device__ __forceinline__ short f2bf(float f) {
    unsigned u = __builtin_bit_cast(unsigned, f);
    u = u + 0x7FFFu + ((u >> 16) & 1u);
    return (short)(u >> 16);
}
__device__ __forceinline__ float bf2f(short s) {
    return __builtin_bit_cast(float, (unsigned)(unsigned short)s << 16);
}

__device__ float g_ktab[32 * 768];                // [b][rr][g][j][12] att-folded taps
__device__ short g_whi[4096], g_wlo[4096];        // conv_w bf16 hi/lo, [o*64+c]

// ---------- prep: b<32 -> att-folded kernels; b==32 -> W hi/lo split ----------
__global__ __launch_bounds__(64) void dgfem_prep(
    const float* __restrict__ v, const float* __restrict__ ca_w1,
    const float* __restrict__ ca_w2, const float* __restrict__ k_w1,
    const float* __restrict__ k_w2, const float* __restrict__ conv_w)
{
    const int b = blockIdx.x;
    const int t = threadIdx.x;           // 64 threads

    if (b == 32) {
        for (int i = t; i < 4096; i += 64) {
            float wv = conv_w[i];
            short hi = f2bf(wv);
            short lo = f2bf(wv - bf2f(hi));
            g_whi[i] = hi;
            g_wlo[i] = lo;
        }
        return;
    }

    __shared__ float vb[64], t1[8], att[64], t2[64];
    vb[t] = v[b * 64 + t];
    __syncthreads();

    if (t < 8) {
        float s = 0.f;
        for (int j = 0; j < 64; ++j) s += vb[j] * ca_w1[t * 64 + j];
        t1[t] = lrelu(s);
    }
    {
        float s = 0.f;
        for (int j = 0; j < 64; ++j) s += vb[j] * k_w1[t * 64 + j];
        t2[t] = lrelu(s);
    }
    __syncthreads();
    {
        float s = 0.f;
        for (int i = 0; i < 8; ++i) s += t1[i] * ca_w2[t * 8 + i];
        att[t] = 1.f / (1.f + expf(-s));
    }
    __syncthreads();
    // fold att[c] into kernel; layout [rr][g][j][12]
    for (int r = t; r < 576; r += 64) {
        int c = r / 9, tp = r - c * 9;
        float s = 0.f;
        for (int j = 0; j < 64; ++j) s += t2[j] * k_w2[r * 64 + j];
        int rr = c >> 4, gg = (c >> 3) & 1, jj = c & 7;
        g_ktab[b * 768 + ((rr * 2 + gg) * 8 + jj) * 12 + tp] = s * att[c];
    }
}

__global__ __launch_bounds__(512) void dgfem_main(
    const float* __restrict__ x0, const float* __restrict__ conv_b,
    float* __restrict__ out)
{
    const int t  = threadIdx.x;          // 512 threads = 8 waves
    const int w  = t >> 6;
    const int l  = t & 63;
    const int g  = l >> 5;               // k-half
    const int ln = l & 31;
    const int G  = w >> 2;               // row group (0/1)
    const int wv = w & 3;                // px tile within group
    const int px = wv * 32 + ln;

    // XCD swizzle (2048 % 8 == 0, bijective)
    const int bid  = blockIdx.x;
    const int orig = (bid & 7) * 256 + (bid >> 3);
    const int b    = orig >> 6;          // 0..31
    const int p    = orig & 63;          // row pair
    const int gy0  = p * 2;
    const int gy   = gy0 + G;            // this thread's output row
    const int r0   = min(max(gy0 - 1, 0), 124);   // first of 4 staged rows

    // per-group slot offsets (floats; row stride 128, masked rows clamped)
    const int sA = (min(max(gy - 1, 0), 127) - r0) * 128;
    const int sB = (gy - r0) * 128;
    const int sC = (min(gy + 1, 127) - r0) * 128;

    __shared__ __align__(16) char lds[LDS_BYTES];
    float* ldsf = (float*)lds;

    // stage both ktab copies with per-group row masks folded in
    {
        const float* ksrc = g_ktab + b * 768;
        const float m0 = (gy0 > 0)       ? 1.f : 0.f;   // group0 top-row mask
        const float m1 = (gy0 + 1 < 127) ? 1.f : 0.f;   // group1 bottom-row mask
        for (int i = t; i < 768; i += 512) {
            int tp = i % 12;
            float val = (tp < 9) ? ksrc[i] : 0.f;
            float f0 = (tp < 3) ? m0 : 1.f;
            float f1 = (tp >= 6 && tp < 9) ? m1 : 1.f;
            *(float*)(lds + KTb + i * 4)        = val * f0;
            *(float*)(lds + KTb + 3072 + i * 4) = val * f1;
        }
    }

    const char* xb = (const char*)x0 + ((size_t)b << 22);
    const int   l16 = l * 16;

    // stage 16 ch x 4 contiguous rows (2048 B/ch); wave w -> channels 2w,2w+1
    #define STAGE(rr_, sel_)                                                   \
    {                                                                          \
        _Pragma("unroll")                                                      \
        for (int u = 0; u < 4; ++u) {                                          \
            const int cc = 2 * w + (u >> 1);                                   \
            const int q  = u & 1;                                              \
            const char* src = xb + ((size_t)((rr_) * 16 + cc) << 16)           \
                              + (size_t)r0 * 512 + q * 1024 + l16;             \
            char* dst = lds + XBb + (sel_) * 32768 + cc * 2048 + q * 1024;     \
            __builtin_amdgcn_global_load_lds(                                  \
                (const __attribute__((address_space(1))) unsigned*)src,        \
                (__attribute__((address_space(3))) unsigned*)dst, 16, 0, 0);   \
        }                                                                      \
    }

    f16x acc0, acc1;
    #pragma unroll
    for (int i = 0; i < 16; ++i) { acc0[i] = 0.f; acc1[i] = 0.f; }

    const int   woffb = ln * 128 + g * 16;
    const float mLf = (px > 0)   ? 1.f : 0.f;
    const float mRf = (px < 127) ? 1.f : 0.f;

    STAGE(0, 0);
    __syncthreads();

    #pragma unroll 1
    for (int rr = 0; rr < 4; ++rr) {
        const int sel = rr & 1;
        if (rr < 3) STAGE(rr + 1, sel ^ 1);

        // row base pointers (j adds j*512 floats -> immediate-foldable)
        const float* xbase = ldsf + (XBf + sel * 8192 + g * 8 * 512 + px - 1);
        const float* bA = xbase + sA;
        const float* bB = xbase + sB;
        const float* bC = xbase + sC;
        const char*  kb = lds + KTb + G * 3072 + (rr * 2 + g) * 384;

        bfrag yh, yl;
        #pragma unroll
        for (int j = 0; j < 8; ++j) {
            const f4* kf = (const f4*)(kb + j * 48);
            f4 kA = kf[0], kB = kf[1], kC = kf[2];
            float xL0 = bA[j * 512]     * mLf;
            float xC0 = bA[j * 512 + 1];
            float xR0 = bA[j * 512 + 2] * mRf;
            float xL1 = bB[j * 512]     * mLf;
            float xC1 = bB[j * 512 + 1];
            float xR1 = bB[j * 512 + 2] * mRf;
            float xL2 = bC[j * 512]     * mLf;
            float xC2 = bC[j * 512 + 1];
            float xR2 = bC[j * 512 + 2] * mRf;
            float a = fmaf(kA.x, xL0, fmaf(kA.y, xC0, kA.z * xR0))
                    + fmaf(kA.w, xL1, fmaf(kB.x, xC1, kB.y * xR1))
                    + fmaf(kB.z, xL2, fmaf(kB.w, xC2, kC.x * xR2));
            a = lrelu(a);
            unsigned u  = __builtin_bit_cast(unsigned, a);
            float   hif = __builtin_bit_cast(float, u & 0xFFFF0000u);
            float   lof = a - hif;                   // exact residual
            yh[j] = (short)(u >> 16);
            yl[j] = (short)(__builtin_bit_cast(unsigned, lof) >> 16);
        }

        const char* whb = (const char*)g_whi + woffb + rr * 32;
        const char* wlb = (const char*)g_wlo + woffb + rr * 32;
        bfrag whi0 = *(const bfrag*)(whb);
        bfrag whi1 = *(const bfrag*)(whb + 4096);
        bfrag wlo0 = *(const bfrag*)(wlb);
        bfrag wlo1 = *(const bfrag*)(wlb + 4096);

        acc0 = __builtin_amdgcn_mfma_f32_32x32x16_bf16(whi0, yh, acc0, 0, 0, 0);
        acc0 = __builtin_amdgcn_mfma_f32_32x32x16_bf16(whi0, yl, acc0, 0, 0, 0);
        acc0 = __builtin_amdgcn_mfma_f32_32x32x16_bf16(wlo0, yh, acc0, 0, 0, 0);
        acc1 = __builtin_amdgcn_mfma_f32_32x32x16_bf16(whi1, yh, acc1, 0, 0, 0);
        acc1 = __builtin_amdgcn_mfma_f32_32x32x16_bf16(whi1, yl, acc1, 0, 0, 0);
        acc1 = __builtin_amdgcn_mfma_f32_32x32x16_bf16(wlo1, yh, acc1, 0, 0, 0);

        __syncthreads();   // stage rr+1 landed; all reads of buf sel done
    }
    #undef STAGE

    // epilogue: D layout col=lane&31, row=(reg&3)+8*(reg>>2)+4*(lane>>5)  [verified 6x]
    float* ob = out + ((size_t)b << 20) + (size_t)gy * HW + px;
    #pragma unroll
    for (int q = 0; q < 4; ++q) {
        const int obase = 8 * q + 4 * g;
        float4 bv0 = *(const float4*)&conv_b[obase];
        float4 bv1 = *(const float4*)&conv_b[32 + obase];
        const float* b0f = (const float*)&bv0;
        const float* b1f = (const float*)&bv1;
        #pragma unroll
        for (int r2 = 0; r2 < 4; ++r2) {
            ob[(size_t)(obase + r2) * 16384]      = acc0[q * 4 + r2] + b0f[r2];
            ob[(size_t)(32 + obase + r2) * 16384] = acc1[q * 4 + r2] + b1f[r2];
        }
    }
}

extern "C" void kernel_launch(void* const* d_in, const int* in_sizes, int n_in,
                              void* d_out, int out_size, void* d_ws, size_t ws_size,
                              hipStream_t stream) {
    const float* x0     = (const float*)d_in[0];
    const float* v      = (const float*)d_in[1];
    const float* ca_w1  = (const float*)d_in[2];
    const float* ca_w2  = (const float*)d_in[3];
    const float* k_w1   = (const float*)d_in[4];
    const float* k_w2   = (const float*)d_in[5];
    const float* conv_w = (const float*)d_in[6];
    const float* conv_b = (const float*)d_in[7];
    float* outp = (float*)d_out;

    dgfem_prep<<<dim3(33), dim3(64), 0, stream>>>(v, ca_w1, ca_w2, k_w1, k_w2, conv_w);
    dgfem_main<<<dim3(2048), dim3(512), 0, stream>>>(x0, conv_b, outp);
}